// Round 6
// baseline (105.898 us; speedup 1.0000x reference)
//
#include <hip/hip_runtime.h>
#include <hip/hip_bf16.h>

typedef __bf16 bf16_t;
typedef __bf16 bf16x4 __attribute__((ext_vector_type(4)));
typedef __bf16 bf16x8 __attribute__((ext_vector_type(8)));
typedef float f32x4 __attribute__((ext_vector_type(4)));
typedef float f32x16 __attribute__((ext_vector_type(16)));

#define BATCH 128
#define NS 512
#define DIM 256
#define BT 128    // output tile (M = N = 128)
#define NT 10     // upper-triangular 4x4 tile count
#define BK 64     // K per staged step
#define LDSK 72   // padded k-stride (144 B rows)

// =================== Kernel B: St = S^T fused with denom partials ===================
__global__ __launch_bounds__(256) void st_denom_kernel(const float* __restrict__ S,
                                                       float* __restrict__ St,
                                                       float* __restrict__ dpartial) {
    const int bi = blockIdx.x >> 4, bj = blockIdx.x & 15;
    const int t  = threadIdx.x;
    const int c  = t & 31, r0 = t >> 5;
    __shared__ float tileS[32][33];
    __shared__ float red[4];
    float dacc = 0.0f;
#pragma unroll
    for (int k = 0; k < 4; ++k) {
        const int r  = r0 + k * 8;
        const int gi = bi * 32 + r, gj = bj * 32 + c;
        const float s = S[(size_t)gi * NS + gj];
        tileS[r][c] = s;
        const float w = (s > 0.0f) ? 1.0f : 0.0f;
        const float e = (gi == gj) ? 1.0f : 0.0f;
        const float d = w - e;
        dacc += d * d;
    }
    __syncthreads();
#pragma unroll
    for (int k = 0; k < 4; ++k) {
        const int r = r0 + k * 8;
        St[(size_t)(bj * 32 + r) * NS + bi * 32 + c] = tileS[c][r];
    }
    const int lane = t & 63, wave = t >> 6;
#pragma unroll
    for (int off = 32; off >= 1; off >>= 1) dacc += __shfl_down(dacc, off, 64);
    if (lane == 0) red[wave] = dacc;
    __syncthreads();
    if (t == 0) dpartial[blockIdx.x] = red[0] + red[1] + red[2] + red[3];
}

// =================== Kernel C: fused gram, BK=64 steps, 3 blocks/CU ===================
// grid 1280 x 512 threads (8 waves, 2x4); wave owns 64x32 = 2 x mfma_32x32.
// Stages fp32 -> norms fma -> bf16 convert -> LDS, 64 k-columns per step.
__global__ __launch_bounds__(512, 6) void gram_fused_kernel(const float* __restrict__ dv,
                                                            const float* __restrict__ S,
                                                            const float* __restrict__ St,
                                                            float* __restrict__ partial) {
    const int bid  = blockIdx.x;
    const int work = (bid & 7) * 160 + (bid >> 3);   // bijective XCD swizzle (1280 = 8*160)
    const int b    = work / NT;
    const int idx  = work - b * NT;
    int ti, tj;
    if (idx < 4)      { ti = 0; tj = idx; }
    else if (idx < 7) { ti = 1; tj = idx - 3; }
    else if (idx < 9) { ti = 2; tj = idx - 5; }
    else              { ti = 3; tj = 3; }
    const bool diag = (ti == tj);
    const int t    = threadIdx.x;
    const int wave = t >> 6, lane = t & 63;
    const int wr   = wave >> 2, wc = wave & 3;
    const int col  = lane & 31, kh = lane >> 5;

    __shared__ bf16_t sA[BT * LDSK];
    __shared__ bf16_t sB[BT * LDSK];
    __shared__ float n2A[BT];
    __shared__ float n2B[BT];
    __shared__ float red[8];

    // staging geometry: 4 threads per row, 16 consecutive k each per step
    const int r = t >> 2, q = t & 3;
    const float* Arow = dv + ((size_t)b * NS + (size_t)ti * BT + r) * DIM + q * 16;
    const float* Brow = dv + ((size_t)b * NS + (size_t)tj * BT + r) * DIM + q * 16;
    bf16_t* sAw = &sA[r * LDSK + q * 16];
    bf16_t* sBw = &sB[r * LDSK + q * 16];
    float na = 0.0f, nb = 0.0f;

    // K-loop addressing (per wave)
    const int arow0 = (wr * 64 + col) * LDSK;
    const int arow1 = (wr * 64 + 32 + col) * LDSK;
    const int brow  = (wc * 32 + col) * LDSK;
    const int kb    = kh * 8;

    f32x16 acc0 = (f32x16)(0.0f);
    f32x16 acc1 = (f32x16)(0.0f);

#pragma unroll
    for (int step = 0; step < 4; ++step) {
        const int ks = step * BK;
        __syncthreads();   // previous step's LDS reads done (no-op cost on step 0)

        // ---- stage: 8 (or 4 on diag) f32x4 loads, norms fma, cvt, ds_write ----
        f32x4 a[4], bq[4];
#pragma unroll
        for (int i = 0; i < 4; ++i) a[i] = *reinterpret_cast<const f32x4*>(Arow + ks + i * 4);
        if (!diag) {
#pragma unroll
            for (int i = 0; i < 4; ++i) bq[i] = *reinterpret_cast<const f32x4*>(Brow + ks + i * 4);
        }
#pragma unroll
        for (int i = 0; i < 4; ++i)
            na += a[i][0]*a[i][0] + a[i][1]*a[i][1] + a[i][2]*a[i][2] + a[i][3]*a[i][3];
        bf16x8 ha0 = { (bf16_t)a[0][0], (bf16_t)a[0][1], (bf16_t)a[0][2], (bf16_t)a[0][3],
                       (bf16_t)a[1][0], (bf16_t)a[1][1], (bf16_t)a[1][2], (bf16_t)a[1][3] };
        bf16x8 ha1 = { (bf16_t)a[2][0], (bf16_t)a[2][1], (bf16_t)a[2][2], (bf16_t)a[2][3],
                       (bf16_t)a[3][0], (bf16_t)a[3][1], (bf16_t)a[3][2], (bf16_t)a[3][3] };
        *reinterpret_cast<bf16x8*>(sAw)     = ha0;
        *reinterpret_cast<bf16x8*>(sAw + 8) = ha1;
        if (!diag) {
#pragma unroll
            for (int i = 0; i < 4; ++i)
                nb += bq[i][0]*bq[i][0] + bq[i][1]*bq[i][1] + bq[i][2]*bq[i][2] + bq[i][3]*bq[i][3];
            bf16x8 hb0 = { (bf16_t)bq[0][0], (bf16_t)bq[0][1], (bf16_t)bq[0][2], (bf16_t)bq[0][3],
                           (bf16_t)bq[1][0], (bf16_t)bq[1][1], (bf16_t)bq[1][2], (bf16_t)bq[1][3] };
            bf16x8 hb1 = { (bf16_t)bq[2][0], (bf16_t)bq[2][1], (bf16_t)bq[2][2], (bf16_t)bq[2][3],
                           (bf16_t)bq[3][0], (bf16_t)bq[3][1], (bf16_t)bq[3][2], (bf16_t)bq[3][3] };
            *reinterpret_cast<bf16x8*>(sBw)     = hb0;
            *reinterpret_cast<bf16x8*>(sBw + 8) = hb1;
        }
        if (step == 3) {   // norms complete: reduce over the 4 k-quarters (lane bits 0-1)
            na += __shfl_xor(na, 1, 64);
            na += __shfl_xor(na, 2, 64);
            if (!diag) {
                nb += __shfl_xor(nb, 1, 64);
                nb += __shfl_xor(nb, 2, 64);
            }
            if (q == 0) { n2A[r] = na; n2B[r] = diag ? na : nb; }
        }
        __syncthreads();   // writes visible

        // ---- compute: 4 x (3 ds_read_b128 + 2 mfma_32x32x16) ----
        const bf16_t* sBp = diag ? sA : sB;
        __builtin_amdgcn_s_setprio(1);
#pragma unroll
        for (int sub = 0; sub < 4; ++sub) {
            const int ko = sub * 16 + kb;
            const bf16x8 a0 = *reinterpret_cast<const bf16x8*>(&sA[arow0 + ko]);
            const bf16x8 a1 = *reinterpret_cast<const bf16x8*>(&sA[arow1 + ko]);
            const bf16x8 bb = *reinterpret_cast<const bf16x8*>(&sBp[brow + ko]);
            acc0 = __builtin_amdgcn_mfma_f32_32x32x16_bf16(a0, bb, acc0, 0, 0, 0);
            acc1 = __builtin_amdgcn_mfma_f32_32x32x16_bf16(a1, bb, acc1, 0, 0, 0);
        }
        __builtin_amdgcn_s_setprio(0);
    }

    // ---- epilogue: C/D 32x32 layout col=lane&31, row=(reg&3)+8*(reg>>2)+4*(lane>>5) ----
    float local = 0.0f;
    {
        const int lj = wc * 32 + col;
        const int gj = tj * BT + lj;
        const float n2j = n2B[lj];
        const float* Srow  = S  + (size_t)gj * NS + (size_t)ti * BT;  // S[gj][gi...]
        const float* Strow = St + (size_t)gj * NS + (size_t)ti * BT;  // St[gj][gi] = S[gi][gj]
#pragma unroll
        for (int m = 0; m < 2; ++m) {
            const f32x16 av = m ? acc1 : acc0;
#pragma unroll
            for (int h = 0; h < 4; ++h) {
                const int li0 = wr * 64 + m * 32 + h * 8 + kh * 4;
                const f32x4 s1q = *reinterpret_cast<const f32x4*>(Strow + li0);
                f32x4 s2q = (f32x4)(0.0f);
                if (!diag) s2q = *reinterpret_cast<const f32x4*>(Srow + li0);
#pragma unroll
                for (int e = 0; e < 4; ++e) {
                    const int li = li0 + e;
                    const float c = av[h * 4 + e];
                    const float sq = fmaxf(n2A[li] + n2j - 2.0f * c, 0.0f);
                    const float dist = sqrtf(sq);
                    const float kd = __expf(-dist);
                    const float s1 = s1q[e];
                    if (diag) {
                        float d = (li == lj) ? (1.0f - s1) : (kd - s1);
                        d *= (s1 > 0.0f) ? 1.0f : 0.0f;
                        local += d * d;
                    } else {
                        const float s2 = s2q[e];
                        const float d1 = (s1 > 0.0f) ? (kd - s1) : 0.0f;
                        const float d2 = (s2 > 0.0f) ? (kd - s2) : 0.0f;
                        local += d1 * d1 + d2 * d2;
                    }
                }
            }
        }
    }
#pragma unroll
    for (int off = 32; off >= 1; off >>= 1) local += __shfl_down(local, off, 64);
    if (lane == 0) red[wave] = local;
    __syncthreads();
    if (t == 0) {
        float s = 0.0f;
#pragma unroll
        for (int w = 0; w < 8; ++w) s += red[w];
        partial[(size_t)b * NT + idx] = s;
    }
}

// =================== fallback path (R2, known-good; used if ws too small) ===================

__global__ __launch_bounds__(256) void norms_kernel(const float* __restrict__ dv,
                                                    float* __restrict__ n2) {
    const int row  = blockIdx.x * 4 + (threadIdx.x >> 6);
    const int lane = threadIdx.x & 63;
    const float4 v = *reinterpret_cast<const float4*>(dv + (size_t)row * DIM + lane * 4);
    float s = v.x * v.x + v.y * v.y + v.z * v.z + v.w * v.w;
#pragma unroll
    for (int off = 32; off >= 1; off >>= 1) s += __shfl_down(s, off, 64);
    if (lane == 0) n2[row] = s;
}

__global__ __launch_bounds__(256) void denom_kernel(const float* __restrict__ Smat,
                                                    float* __restrict__ dpartial) {
    const int t = threadIdx.x;
    const int lane = t & 63, wave = t >> 6;
    __shared__ float sred[4];
    float acc = 0.0f;
    const int base = blockIdx.x * 512;
#pragma unroll
    for (int r = 0; r < 2; ++r) {
        const int v4 = base + r * 256 + t;
        const float4 s4 = reinterpret_cast<const float4*>(Smat)[v4];
        const int idx0 = v4 * 4;
        const int i = idx0 >> 9;
#pragma unroll
        for (int c = 0; c < 4; ++c) {
            const float s = (&s4.x)[c];
            const int j = (idx0 + c) & (NS - 1);
            const float w = (s > 0.0f) ? 1.0f : 0.0f;
            const float e = (i == j) ? 1.0f : 0.0f;
            const float d = w - e;
            acc += d * d;
        }
    }
#pragma unroll
    for (int off = 32; off >= 1; off >>= 1) acc += __shfl_down(acc, off, 64);
    if (lane == 0) sred[wave] = acc;
    __syncthreads();
    if (t == 0) dpartial[blockIdx.x] = sred[0] + sred[1] + sred[2] + sred[3];
}

#define FLDSK 40
__global__ __launch_bounds__(256) void gram_f32_kernel(const float* __restrict__ dv,
                                                       const float* __restrict__ Smat,
                                                       const float* __restrict__ n2,
                                                       float* __restrict__ partial) {
    const int tile = blockIdx.x;
    const int b    = blockIdx.y;
    const int ti   = tile >> 2, tj = tile & 3;
    const int t    = threadIdx.x;
    const int wave = t >> 6, lane = t & 63;
    const int wr   = wave >> 1, wc = wave & 1;

    __shared__ bf16_t sA[BT * FLDSK];
    __shared__ bf16_t sB[BT * FLDSK];
    __shared__ float red[4];

    const float* Abase = dv + ((size_t)b * NS + (size_t)ti * BT) * DIM;
    const float* Bbase = dv + ((size_t)b * NS + (size_t)tj * BT) * DIM;

    f32x4 acc[4][4];
#pragma unroll
    for (int m = 0; m < 4; ++m)
#pragma unroll
        for (int n = 0; n < 4; ++n) acc[m][n] = (f32x4)(0.0f);

    const int fr = lane & 15;
    const int g  = lane >> 4;

    for (int ks = 0; ks < DIM; ks += 32) {
        float4 ra[4], rb[4];
#pragma unroll
        for (int i = 0; i < 4; ++i) {
            const int c   = i * 256 + t;
            const int row = c >> 3;
            const int kc  = (c & 7) * 4;
            ra[i] = *reinterpret_cast<const float4*>(Abase + (size_t)row * DIM + ks + kc);
            rb[i] = *reinterpret_cast<const float4*>(Bbase + (size_t)row * DIM + ks + kc);
        }
        __syncthreads();
#pragma unroll
        for (int i = 0; i < 4; ++i) {
            const int c   = i * 256 + t;
            const int row = c >> 3;
            const int kc  = (c & 7) * 4;
            bf16x4 va = { (bf16_t)ra[i].x, (bf16_t)ra[i].y, (bf16_t)ra[i].z, (bf16_t)ra[i].w };
            bf16x4 vb = { (bf16_t)rb[i].x, (bf16_t)rb[i].y, (bf16_t)rb[i].z, (bf16_t)rb[i].w };
            *reinterpret_cast<bf16x4*>(&sA[row * FLDSK + kc]) = va;
            *reinterpret_cast<bf16x4*>(&sB[row * FLDSK + kc]) = vb;
        }
        __syncthreads();

        bf16x8 afrag[4], bfrag[4];
#pragma unroll
        for (int m = 0; m < 4; ++m)
            afrag[m] = *reinterpret_cast<const bf16x8*>(&sA[(wr * 64 + m * 16 + fr) * FLDSK + g * 8]);
#pragma unroll
        for (int n = 0; n < 4; ++n)
            bfrag[n] = *reinterpret_cast<const bf16x8*>(&sB[(wc * 64 + n * 16 + fr) * FLDSK + g * 8]);
#pragma unroll
        for (int m = 0; m < 4; ++m)
#pragma unroll
            for (int n = 0; n < 4; ++n)
                acc[m][n] = __builtin_amdgcn_mfma_f32_16x16x32_bf16(afrag[m], bfrag[n], acc[m][n], 0, 0, 0);
    }

    float local = 0.0f;
    const float* n2b = n2 + (size_t)b * NS;
    const int rowbase = ti * BT + wr * 64;
    const int colbase = tj * BT + wc * 64;
#pragma unroll
    for (int m = 0; m < 4; ++m) {
#pragma unroll
        for (int n = 0; n < 4; ++n) {
            const int gi0 = rowbase + m * 16 + g * 4;
            const int gj  = colbase + n * 16 + fr;
            const float ncol = n2b[gj];
#pragma unroll
            for (int j = 0; j < 4; ++j) {
                const int gi = gi0 + j;
                const float cij = acc[m][n][j];
                float sq = fmaxf(n2b[gi] + ncol - 2.0f * cij, 0.0f);
                const float dist = sqrtf(sq);
                const float kd = __expf(-dist);
                const float s = Smat[(size_t)gi * NS + gj];
                const float w = (s > 0.0f) ? 1.0f : 0.0f;
                float d = (gi == gj) ? (1.0f - s) : (kd - s);
                d *= w;
                local += d * d;
            }
        }
    }
#pragma unroll
    for (int off = 32; off >= 1; off >>= 1) local += __shfl_down(local, off, 64);
    if (lane == 0) red[wave] = local;
    __syncthreads();
    if (t == 0) partial[(size_t)b * 16 + tile] = red[0] + red[1] + red[2] + red[3];
}

// =================== shared finalize ===================
__global__ __launch_bounds__(256) void finalize_kernel(const float* __restrict__ dpartial, int ndp,
                                                       const float* __restrict__ partial, int ntiles,
                                                       float* __restrict__ out) {
    const int t = threadIdx.x;
    const int lane = t & 63, wave = t >> 6;
    __shared__ float sred[4];
    __shared__ float sred2[4];

    float dacc = (t < ndp) ? dpartial[t] : 0.0f;
#pragma unroll
    for (int off = 32; off >= 1; off >>= 1) dacc += __shfl_down(dacc, off, 64);
    if (lane == 0) sred[wave] = dacc;
    __syncthreads();
    const float denom = sqrtf(sred[0] + sred[1] + sred[2] + sred[3]);

    float lsum = 0.0f;
    if (t < BATCH) {
        float ss = 0.0f;
        for (int k = 0; k < ntiles; ++k) ss += partial[(size_t)t * ntiles + k];
        lsum = 2.0f * sqrtf(ss) / denom;
    }
#pragma unroll
    for (int off = 32; off >= 1; off >>= 1) lsum += __shfl_down(lsum, off, 64);
    if (lane == 0) sred2[wave] = lsum;
    __syncthreads();
    if (t == 0) out[0] = sred2[0] + sred2[1] + sred2[2] + sred2[3];
}

extern "C" void kernel_launch(void* const* d_in, const int* in_sizes, int n_in,
                              void* d_out, int out_size, void* d_ws, size_t ws_size,
                              hipStream_t stream) {
    const float* dv   = (const float*)d_in[0];   // [128,512,256] fp32
    const float* Smat = (const float*)d_in[1];   // [512,512] fp32
    float* out = (float*)d_out;

    const size_t st_bytes = (size_t)NS * NS * 4;          // 1 MB
    const size_t pt_bytes = (size_t)BATCH * 16 * 4;
    const size_t dp_bytes = 256 * 4;
    const size_t need = st_bytes + pt_bytes + dp_bytes;

    if (ws_size >= need) {
        char* w = (char*)d_ws;
        float* St      = (float*)w;   w += st_bytes;
        float* partial = (float*)w;   w += pt_bytes;
        float* dpart   = (float*)w;

        st_denom_kernel<<<dim3(256), 256, 0, stream>>>(Smat, St, dpart);
        gram_fused_kernel<<<dim3(NT * BATCH), 512, 0, stream>>>(dv, Smat, St, partial);
        finalize_kernel<<<dim3(1), 256, 0, stream>>>(dpart, 256, partial, NT, out);
    } else {
        float* n2      = (float*)d_ws;
        float* partial = n2 + (size_t)BATCH * NS;
        float* dpart   = partial + (size_t)BATCH * 16;

        norms_kernel<<<dim3(BATCH * NS / 4), 256, 0, stream>>>(dv, n2);
        denom_kernel<<<dim3(128), 256, 0, stream>>>(Smat, dpart);
        gram_f32_kernel<<<dim3(16, BATCH), 256, 0, stream>>>(dv, Smat, n2, partial);
        finalize_kernel<<<dim3(1), 256, 0, stream>>>(dpart, 128, partial, 16, out);
    }
}

// Round 7
// 58.065 us; speedup vs baseline: 1.8238x; 1.8238x over previous
//
#include <hip/hip_runtime.h>
#include <hip/hip_bf16.h>

typedef __bf16 bf16_t;
typedef __bf16 bf16x4 __attribute__((ext_vector_type(4)));
typedef __bf16 bf16x8 __attribute__((ext_vector_type(8)));
typedef float f32x4 __attribute__((ext_vector_type(4)));
typedef float f32x16 __attribute__((ext_vector_type(16)));
typedef long i64x2 __attribute__((ext_vector_type(2)));
typedef int i32x4 __attribute__((ext_vector_type(4)));

#define BATCH 128
#define NS 512
#define DIM 256
#define BT 128
#define LDSP 272   // bytes per 256-fp8 row: 16B-aligned, word-stride 68 (==4 mod 32) -> uniform banks

// =================== Kernel B: St = S^T fused with denom partials ===================
__global__ __launch_bounds__(256) void st_denom_kernel(const float* __restrict__ S,
                                                       float* __restrict__ St,
                                                       float* __restrict__ dpartial) {
    const int bi = blockIdx.x >> 4, bj = blockIdx.x & 15;
    const int t  = threadIdx.x;
    const int c  = t & 31, r0 = t >> 5;
    __shared__ float tileS[32][33];
    __shared__ float red[4];
    float dacc = 0.0f;
#pragma unroll
    for (int k = 0; k < 4; ++k) {
        const int r  = r0 + k * 8;
        const int gi = bi * 32 + r, gj = bj * 32 + c;
        const float s = S[(size_t)gi * NS + gj];
        tileS[r][c] = s;
        const float w = (s > 0.0f) ? 1.0f : 0.0f;
        const float e = (gi == gj) ? 1.0f : 0.0f;
        const float d = w - e;
        dacc += d * d;
    }
    __syncthreads();
#pragma unroll
    for (int k = 0; k < 4; ++k) {
        const int r = r0 + k * 8;
        St[(size_t)(bj * 32 + r) * NS + bi * 32 + c] = tileS[c][r];
    }
    const int lane = t & 63, wave = t >> 6;
#pragma unroll
    for (int off = 32; off >= 1; off >>= 1) dacc += __shfl_down(dacc, off, 64);
    if (lane == 0) red[wave] = dacc;
    __syncthreads();
    if (t == 0) dpartial[blockIdx.x] = red[0] + red[1] + red[2] + red[3];
}

// =================== Kernel C: fp8 stage-once gram, 1 barrier, 5 tiles/block ===================
// grid 256 x 512 threads. Block = (batch, half). Half 0: tiles (0,0),(0,1),(0,2),(0,3),(1,1);
// half 1: (1,2),(1,3),(2,2),(2,3),(3,3). All 4 panels of the batch staged as fp8 in LDS once.
__global__ __launch_bounds__(512) void gram_fp8_kernel(const float* __restrict__ dv,
                                                       const float* __restrict__ S,
                                                       const float* __restrict__ St,
                                                       float* __restrict__ partial) {
    const int bid  = blockIdx.x;
    const int work = (bid & 7) * 32 + (bid >> 3);   // XCD x owns batches [x*16,(x+1)*16)
    const int b    = work >> 1, h = work & 1;
    const int t    = threadIdx.x;
    const int wave = t >> 6, lane = t & 63;
    const int wr   = wave >> 2, wc = wave & 3;      // 2x4 wave grid; wave owns 64x32
    const int col  = lane & 31, kh = lane >> 5;

    __shared__ char  sP[512 * LDSP];   // 4 panels x 128 rows x 256 fp8 (+pad)
    __shared__ float n2s[512];
    __shared__ float red[8];

    // ---- staging: fp32 read -> exact fp32 norms -> fp8 cvt -> LDS; panel 0 skipped for h==1 ----
    {
        const int r = t >> 2, q = t & 3;   // 4 threads/row, 64 floats each
        for (int p = h; p < 4; ++p) {
            const float* rowp = dv + ((size_t)b * NS + p * 128 + r) * DIM + q * 64;
            float na = 0.0f;
            int pk[16];
#pragma unroll
            for (int i = 0; i < 16; ++i) {
                const f32x4 v = *reinterpret_cast<const f32x4*>(rowp + i * 4);
                na += v[0]*v[0] + v[1]*v[1] + v[2]*v[2] + v[3]*v[3];
                int w0 = __builtin_amdgcn_cvt_pk_fp8_f32(v[0], v[1], 0, false);
                w0     = __builtin_amdgcn_cvt_pk_fp8_f32(v[2], v[3], w0, true);
                pk[i] = w0;
            }
            char* wbase = &sP[(p * 128 + r) * LDSP + q * 64];
#pragma unroll
            for (int j = 0; j < 4; ++j) {
                i32x4 wv = { pk[4*j], pk[4*j+1], pk[4*j+2], pk[4*j+3] };
                *reinterpret_cast<i32x4*>(wbase + j * 16) = wv;
            }
            na += __shfl_xor(na, 1, 64);
            na += __shfl_xor(na, 2, 64);
            if (q == 0) n2s[p * 128 + r] = na;
        }
    }
    __syncthreads();   // the ONLY data barrier

    // ---- 5 tiles: pure LDS->reg MFMA + fused epilogue, no barriers ----
    float local = 0.0f;
#pragma unroll 1
    for (int tt = 0; tt < 5; ++tt) {
        int ti, tj;
        if (h == 0) { ti = (tt == 4) ? 1 : 0; tj = (tt < 4) ? tt : 1; }
        else        { ti = 1 + (tt >> 1);     tj = (tt < 4) ? 2 + (tt & 1) : 3; }
        const bool diag = (ti == tj);

        const char* aP = &sP[(ti * 128 + wr * 64 + col) * LDSP + kh * 16];
        const char* bP = &sP[(tj * 128 + wc * 32 + col) * LDSP + kh * 16];

        f32x16 acc0 = (f32x16)(0.0f);
        f32x16 acc1 = (f32x16)(0.0f);
        __builtin_amdgcn_s_setprio(1);
#pragma unroll
        for (int u = 0; u < 8; ++u) {
            // b128 holds frags for two k-16 insts; identical k-gather on A and B -> order cancels
            const i64x2 A0 = *reinterpret_cast<const i64x2*>(aP + u * 32);
            const i64x2 A1 = *reinterpret_cast<const i64x2*>(aP + 32 * LDSP + u * 32);
            const i64x2 Bv = *reinterpret_cast<const i64x2*>(bP + u * 32);
            acc0 = __builtin_amdgcn_mfma_f32_32x32x16_fp8_fp8(A0[0], Bv[0], acc0, 0, 0, 0);
            acc1 = __builtin_amdgcn_mfma_f32_32x32x16_fp8_fp8(A1[0], Bv[0], acc1, 0, 0, 0);
            acc0 = __builtin_amdgcn_mfma_f32_32x32x16_fp8_fp8(A0[1], Bv[1], acc0, 0, 0, 0);
            acc1 = __builtin_amdgcn_mfma_f32_32x32x16_fp8_fp8(A1[1], Bv[1], acc1, 0, 0, 0);
        }
        __builtin_amdgcn_s_setprio(0);

        // epilogue: C/D 32x32 layout col=lane&31, row=(reg&3)+8*(reg>>2)+4*(lane>>5)
        const int lj = wc * 32 + col;
        const int gj = tj * BT + lj;
        const float n2j = n2s[tj * 128 + lj];
        const float* Srow  = S  + (size_t)gj * NS + ti * BT;   // S[gj][gi...]  (mirror)
        const float* Strow = St + (size_t)gj * NS + ti * BT;   // St[gj][gi] = S[gi][gj]
#pragma unroll
        for (int m = 0; m < 2; ++m) {
            const f32x16 av = m ? acc1 : acc0;
#pragma unroll
            for (int h4 = 0; h4 < 4; ++h4) {
                const int li0 = wr * 64 + m * 32 + h4 * 8 + kh * 4;
                const f32x4 s1q = *reinterpret_cast<const f32x4*>(Strow + li0);
                f32x4 s2q = (f32x4)(0.0f);
                if (!diag) s2q = *reinterpret_cast<const f32x4*>(Srow + li0);
#pragma unroll
                for (int e = 0; e < 4; ++e) {
                    const int li = li0 + e;
                    const float c = av[h4 * 4 + e];
                    const float sq = fmaxf(n2s[ti * 128 + li] + n2j - 2.0f * c, 0.0f);
                    const float dist = sqrtf(sq);
                    const float kd = __expf(-dist);
                    const float s1 = s1q[e];
                    if (diag) {
                        float d = (li == lj) ? (1.0f - s1) : (kd - s1);
                        d *= (s1 > 0.0f) ? 1.0f : 0.0f;
                        local += d * d;
                    } else {
                        const float s2 = s2q[e];
                        const float d1 = (s1 > 0.0f) ? (kd - s1) : 0.0f;
                        const float d2 = (s2 > 0.0f) ? (kd - s2) : 0.0f;
                        local += d1 * d1 + d2 * d2;
                    }
                }
            }
        }
    }

#pragma unroll
    for (int off = 32; off >= 1; off >>= 1) local += __shfl_down(local, off, 64);
    if (lane == 0) red[wave] = local;
    __syncthreads();
    if (t == 0) {
        float s = 0.0f;
#pragma unroll
        for (int w = 0; w < 8; ++w) s += red[w];
        partial[(size_t)b * 2 + h] = s;
    }
}

// =================== fallback path (R2, known-good; used if ws too small) ===================

__global__ __launch_bounds__(256) void norms_kernel(const float* __restrict__ dv,
                                                    float* __restrict__ n2) {
    const int row  = blockIdx.x * 4 + (threadIdx.x >> 6);
    const int lane = threadIdx.x & 63;
    const float4 v = *reinterpret_cast<const float4*>(dv + (size_t)row * DIM + lane * 4);
    float s = v.x * v.x + v.y * v.y + v.z * v.z + v.w * v.w;
#pragma unroll
    for (int off = 32; off >= 1; off >>= 1) s += __shfl_down(s, off, 64);
    if (lane == 0) n2[row] = s;
}

__global__ __launch_bounds__(256) void denom_kernel(const float* __restrict__ Smat,
                                                    float* __restrict__ dpartial) {
    const int t = threadIdx.x;
    const int lane = t & 63, wave = t >> 6;
    __shared__ float sred[4];
    float acc = 0.0f;
    const int base = blockIdx.x * 512;
#pragma unroll
    for (int r = 0; r < 2; ++r) {
        const int v4 = base + r * 256 + t;
        const float4 s4 = reinterpret_cast<const float4*>(Smat)[v4];
        const int idx0 = v4 * 4;
        const int i = idx0 >> 9;
#pragma unroll
        for (int c = 0; c < 4; ++c) {
            const float s = (&s4.x)[c];
            const int j = (idx0 + c) & (NS - 1);
            const float w = (s > 0.0f) ? 1.0f : 0.0f;
            const float e = (i == j) ? 1.0f : 0.0f;
            const float d = w - e;
            acc += d * d;
        }
    }
#pragma unroll
    for (int off = 32; off >= 1; off >>= 1) acc += __shfl_down(acc, off, 64);
    if (lane == 0) sred[wave] = acc;
    __syncthreads();
    if (t == 0) dpartial[blockIdx.x] = sred[0] + sred[1] + sred[2] + sred[3];
}

#define FLDSK 40
__global__ __launch_bounds__(256) void gram_f32_kernel(const float* __restrict__ dv,
                                                       const float* __restrict__ Smat,
                                                       const float* __restrict__ n2,
                                                       float* __restrict__ partial) {
    const int tile = blockIdx.x;
    const int b    = blockIdx.y;
    const int ti   = tile >> 2, tj = tile & 3;
    const int t    = threadIdx.x;
    const int wave = t >> 6, lane = t & 63;
    const int wr   = wave >> 1, wc = wave & 1;

    __shared__ bf16_t sA[BT * FLDSK];
    __shared__ bf16_t sB[BT * FLDSK];
    __shared__ float red[4];

    const float* Abase = dv + ((size_t)b * NS + (size_t)ti * BT) * DIM;
    const float* Bbase = dv + ((size_t)b * NS + (size_t)tj * BT) * DIM;

    f32x4 acc[4][4];
#pragma unroll
    for (int m = 0; m < 4; ++m)
#pragma unroll
        for (int n = 0; n < 4; ++n) acc[m][n] = (f32x4)(0.0f);

    const int fr = lane & 15;
    const int g  = lane >> 4;

    for (int ks = 0; ks < DIM; ks += 32) {
        float4 ra[4], rb[4];
#pragma unroll
        for (int i = 0; i < 4; ++i) {
            const int c   = i * 256 + t;
            const int row = c >> 3;
            const int kc  = (c & 7) * 4;
            ra[i] = *reinterpret_cast<const float4*>(Abase + (size_t)row * DIM + ks + kc);
            rb[i] = *reinterpret_cast<const float4*>(Bbase + (size_t)row * DIM + ks + kc);
        }
        __syncthreads();
#pragma unroll
        for (int i = 0; i < 4; ++i) {
            const int c   = i * 256 + t;
            const int row = c >> 3;
            const int kc  = (c & 7) * 4;
            bf16x4 va = { (bf16_t)ra[i].x, (bf16_t)ra[i].y, (bf16_t)ra[i].z, (bf16_t)ra[i].w };
            bf16x4 vb = { (bf16_t)rb[i].x, (bf16_t)rb[i].y, (bf16_t)rb[i].z, (bf16_t)rb[i].w };
            *reinterpret_cast<bf16x4*>(&sA[row * FLDSK + kc]) = va;
            *reinterpret_cast<bf16x4*>(&sB[row * FLDSK + kc]) = vb;
        }
        __syncthreads();

        bf16x8 afrag[4], bfrag[4];
#pragma unroll
        for (int m = 0; m < 4; ++m)
            afrag[m] = *reinterpret_cast<const bf16x8*>(&sA[(wr * 64 + m * 16 + fr) * FLDSK + g * 8]);
#pragma unroll
        for (int n = 0; n < 4; ++n)
            bfrag[n] = *reinterpret_cast<const bf16x8*>(&sB[(wc * 64 + n * 16 + fr) * FLDSK + g * 8]);
#pragma unroll
        for (int m = 0; m < 4; ++m)
#pragma unroll
            for (int n = 0; n < 4; ++n)
                acc[m][n] = __builtin_amdgcn_mfma_f32_16x16x32_bf16(afrag[m], bfrag[n], acc[m][n], 0, 0, 0);
    }

    float local = 0.0f;
    const float* n2b = n2 + (size_t)b * NS;
    const int rowbase = ti * BT + wr * 64;
    const int colbase = tj * BT + wc * 64;
#pragma unroll
    for (int m = 0; m < 4; ++m) {
#pragma unroll
        for (int n = 0; n < 4; ++n) {
            const int gi0 = rowbase + m * 16 + g * 4;
            const int gj  = colbase + n * 16 + fr;
            const float ncol = n2b[gj];
#pragma unroll
            for (int j = 0; j < 4; ++j) {
                const int gi = gi0 + j;
                const float cij = acc[m][n][j];
                float sq = fmaxf(n2b[gi] + ncol - 2.0f * cij, 0.0f);
                const float dist = sqrtf(sq);
                const float kd = __expf(-dist);
                const float s = Smat[(size_t)gi * NS + gj];
                const float w = (s > 0.0f) ? 1.0f : 0.0f;
                float d = (gi == gj) ? (1.0f - s) : (kd - s);
                d *= w;
                local += d * d;
            }
        }
    }
#pragma unroll
    for (int off = 32; off >= 1; off >>= 1) local += __shfl_down(local, off, 64);
    if (lane == 0) red[wave] = local;
    __syncthreads();
    if (t == 0) partial[(size_t)b * 16 + tile] = red[0] + red[1] + red[2] + red[3];
}

// =================== shared finalize ===================
__global__ __launch_bounds__(256) void finalize_kernel(const float* __restrict__ dpartial, int ndp,
                                                       const float* __restrict__ partial, int ntiles,
                                                       float* __restrict__ out) {
    const int t = threadIdx.x;
    const int lane = t & 63, wave = t >> 6;
    __shared__ float sred[4];
    __shared__ float sred2[4];

    float dacc = (t < ndp) ? dpartial[t] : 0.0f;
#pragma unroll
    for (int off = 32; off >= 1; off >>= 1) dacc += __shfl_down(dacc, off, 64);
    if (lane == 0) sred[wave] = dacc;
    __syncthreads();
    const float denom = sqrtf(sred[0] + sred[1] + sred[2] + sred[3]);

    float lsum = 0.0f;
    if (t < BATCH) {
        float ss = 0.0f;
        for (int k = 0; k < ntiles; ++k) ss += partial[(size_t)t * ntiles + k];
        lsum = 2.0f * sqrtf(ss) / denom;
    }
#pragma unroll
    for (int off = 32; off >= 1; off >>= 1) lsum += __shfl_down(lsum, off, 64);
    if (lane == 0) sred2[wave] = lsum;
    __syncthreads();
    if (t == 0) out[0] = sred2[0] + sred2[1] + sred2[2] + sred2[3];
}

extern "C" void kernel_launch(void* const* d_in, const int* in_sizes, int n_in,
                              void* d_out, int out_size, void* d_ws, size_t ws_size,
                              hipStream_t stream) {
    const float* dv   = (const float*)d_in[0];   // [128,512,256] fp32
    const float* Smat = (const float*)d_in[1];   // [512,512] fp32
    float* out = (float*)d_out;

    const size_t st_bytes = (size_t)NS * NS * 4;          // 1 MB
    const size_t pt_bytes = (size_t)BATCH * 16 * 4;
    const size_t dp_bytes = 256 * 4;
    const size_t need = st_bytes + pt_bytes + dp_bytes;

    if (ws_size >= need) {
        char* w = (char*)d_ws;
        float* St      = (float*)w;   w += st_bytes;
        float* partial = (float*)w;   w += pt_bytes;
        float* dpart   = (float*)w;

        st_denom_kernel<<<dim3(256), 256, 0, stream>>>(Smat, St, dpart);
        gram_fp8_kernel<<<dim3(256), 512, 0, stream>>>(dv, Smat, St, partial);
        finalize_kernel<<<dim3(1), 256, 0, stream>>>(dpart, 256, partial, 2, out);
    } else {
        float* n2      = (float*)d_ws;
        float* partial = n2 + (size_t)BATCH * NS;
        float* dpart   = partial + (size_t)BATCH * 16;

        norms_kernel<<<dim3(BATCH * NS / 4), 256, 0, stream>>>(dv, n2);
        denom_kernel<<<dim3(128), 256, 0, stream>>>(Smat, dpart);
        gram_f32_kernel<<<dim3(16, BATCH), 256, 0, stream>>>(dv, Smat, n2, partial);
        finalize_kernel<<<dim3(1), 256, 0, stream>>>(dpart, 128, partial, 16, out);
    }
}